// Round 2
// baseline (214.009 us; speedup 1.0000x reference)
//
#include <hip/hip_runtime.h>

// NCC loss, fused single pass, 2-barrier software-pipelined plane loop.
// Volume [B=2][1][D=160][H=192][W=160] fp32. Window 9^3, zero-padded, /729.
// Per block: tile TH=16 x TW=32 in (H,W), stream ZC=19 z-planes (NSTEP=27=3*9).
// Pipeline per plane i:  P1 = { A(i+1): global->LDS raw I,J  ||  C(i): H-axis 9-tap }
//                        P2 = { B(i+1): products + W-axis 9-tap ||  D(i): z-ring + cc }
// Single-buffered LDS: every producer->consumer and WAR pair spans exactly 1 barrier.

#define NB 2
#define ND 160
#define NH 192
#define NW 160
#define TH 16
#define TW 32
#define ZC 19
#define NSTEP (ZC + 8)     // 27 planes touched per chunk = 3*9 (static ring slots)
#define ZCHUNKS 9          // ceil(160/19)
#define HR (TH + 8)        // 24 halo rows
#define RSTR 44            // raw row stride (40 cols used; 44 breaks 8r%32 bank cycle)
#define HSTR 36            // hsum row stride (32 used)
#define VSTR 36
#define NTH 512

__device__ __forceinline__ float4 f4add(float4 a, float4 b) {
    return make_float4(a.x + b.x, a.y + b.y, a.z + b.z, a.w + b.w);
}
__device__ __forceinline__ float4 f4sub(float4 a, float4 b) {
    return make_float4(a.x - b.x, a.y - b.y, a.z - b.z, a.w - b.w);
}

__global__ __launch_bounds__(NTH, 6) void ncc_main(
        const float* __restrict__ I, const float* __restrict__ J,
        double* __restrict__ gacc) {
    __shared__ float rawI[HR][RSTR];          // 4.2 KB
    __shared__ float rawJ[HR][RSTR];          // 4.2 KB
    __shared__ float hsum[5][HR + 1][HSTR];   // 17.6 KB (+1 row: field stride 900%32=4)
    __shared__ float vsum[5][TH][VSTR];       // 11.5 KB           total ~37.5 KB

    const int tid = threadIdx.x;
    const int tx = tid & 31;
    const int ty = tid >> 5;

    const int tilesW = NW / TW;                 // 5
    const int tileW = blockIdx.x % tilesW;
    const int tileH = blockIdx.x / tilesW;      // 0..11
    const int w0 = tileW * TW;
    const int h0 = tileH * TH;
    const int z0 = blockIdx.y * ZC;
    const size_t volBase = (size_t)blockIdx.z * ND * NH * NW;

    // ---- A decode: 480 threads; slot in [0,240): 24 rows x 10 float4; I half / J half
    const bool a_on = (tid < 480);
    const bool a_isI = (tid < 240);
    const int a_slot = a_on ? (a_isI ? tid : tid - 240) : 0;
    const int a_r = a_slot / 10;
    const int a_c = (a_slot - a_r * 10) * 4;
    const int a_h = h0 - 4 + a_r;
    const int a_w = w0 - 4 + a_c;   // W edges are multiples of 4: float4 fully in or out
    const bool a_hw = a_on && a_h >= 0 && a_h < NH && a_w >= 0 && a_w < NW;
    const float* a_src = a_isI ? I : J;
    float* a_dst = a_isI ? &rawI[a_r][a_c] : &rawJ[a_r][a_c];
    const size_t a_off = ((size_t)a_h * NW + a_w);

    // ---- B decode: 240 threads: (field, row, half-row of 16 outputs)
    const bool b_on = (tid < 240);
    const int b_f = b_on ? tid / 48 : 0;
    const int b_rem = b_on ? tid - b_f * 48 : 0;
    const int b_r = b_rem >> 1;
    const int b_c0 = (b_rem & 1) << 4;
    const float* b_srcA = (b_f == 1 || b_f == 3) ? &rawJ[b_r][b_c0] : &rawI[b_r][b_c0];
    const float* b_srcB = &rawJ[b_r][b_c0];
    const bool b_sq = (b_f == 2 || b_f == 3);
    const bool b_ij = (b_f == 4);

    // ---- C decode: 160 threads: (field, col-group of 4, row-strip of 4)
    const bool c_on = (tid < 160);
    const int c_f = tid >> 5;
    const int c_cg = (tid & 31) >> 2;
    const int c_r0 = (tid & 3) << 2;
    const int c_c0 = c_cg << 2;

#define DO_A(zt) do {                                                          \
    float4 v = make_float4(0.f, 0.f, 0.f, 0.f);                                \
    if (a_hw) v = *(const float4*)(a_src + volBase + (size_t)(zt) * (NH * NW) + a_off); \
    if (a_on) *(float4*)a_dst = v;                                             \
} while (0)

#define DO_B() do { if (b_on) {                                                \
    float p[24];                                                               \
    _Pragma("unroll") for (int k = 0; k < 6; ++k)                              \
        *(float4*)&p[k * 4] = *(const float4*)(b_srcA + k * 4);                \
    if (b_sq) { _Pragma("unroll") for (int k = 0; k < 24; ++k) p[k] *= p[k]; } \
    if (b_ij) { _Pragma("unroll") for (int k = 0; k < 6; ++k) {                \
        float4 q = *(const float4*)(b_srcB + k * 4);                           \
        p[k*4+0] *= q.x; p[k*4+1] *= q.y; p[k*4+2] *= q.z; p[k*4+3] *= q.w; } }\
    float s = p[0];                                                            \
    _Pragma("unroll") for (int k = 1; k < 9; ++k) s += p[k];                   \
    _Pragma("unroll") for (int g = 0; g < 4; ++g) {                            \
        float4 ov; ov.x = s;                                                   \
        s += p[g*4+9]  - p[g*4+0]; ov.y = s;                                   \
        s += p[g*4+10] - p[g*4+1]; ov.z = s;                                   \
        s += p[g*4+11] - p[g*4+2]; ov.w = s;                                   \
        *(float4*)&hsum[b_f][b_r][b_c0 + g*4] = ov;                            \
        if (g < 3) s += p[g*4+12] - p[g*4+3];                                  \
    } } } while (0)

#define DO_C() do { if (c_on) {                                                \
    float4 r0v = *(const float4*)&hsum[c_f][c_r0 + 0][c_c0];                   \
    float4 r1v = *(const float4*)&hsum[c_f][c_r0 + 1][c_c0];                   \
    float4 r2v = *(const float4*)&hsum[c_f][c_r0 + 2][c_c0];                   \
    float4 s4 = f4add(f4add(r0v, r1v), r2v);                                   \
    _Pragma("unroll") for (int k = 3; k < 9; ++k)                              \
        s4 = f4add(s4, *(const float4*)&hsum[c_f][c_r0 + k][c_c0]);            \
    *(float4*)&vsum[c_f][c_r0 + 0][c_c0] = s4;                                 \
    s4 = f4sub(f4add(s4, *(const float4*)&hsum[c_f][c_r0 +  9][c_c0]), r0v);   \
    *(float4*)&vsum[c_f][c_r0 + 1][c_c0] = s4;                                 \
    s4 = f4sub(f4add(s4, *(const float4*)&hsum[c_f][c_r0 + 10][c_c0]), r1v);   \
    *(float4*)&vsum[c_f][c_r0 + 2][c_c0] = s4;                                 \
    s4 = f4sub(f4add(s4, *(const float4*)&hsum[c_f][c_r0 + 11][c_c0]), r2v);   \
    *(float4*)&vsum[c_f][c_r0 + 3][c_c0] = s4;                                 \
} } while (0)

    float ring[5][9];
    float acc[5];
#pragma unroll
    for (int f = 0; f < 5; ++f) {
        acc[f] = 0.f;
#pragma unroll
        for (int k = 0; k < 9; ++k) ring[f][k] = 0.f;
    }
    float partial = 0.f;

    // ---- prologue: plane 0 through A and B ----
    {
        const int zt0 = z0 - 4;
        if (zt0 >= 0) DO_A(zt0);
        __syncthreads();
        if (zt0 >= 0) DO_B();
        __syncthreads();
    }

#pragma unroll 1
    for (int ii = 0; ii < NSTEP; ii += 9) {
#pragma unroll
        for (int jj = 0; jj < 9; ++jj) {       // jj == i % 9 : static ring slot
            const int i = ii + jj;
            const int zt_cur = z0 - 4 + i;
            const bool zok_cur = (zt_cur >= 0) && (zt_cur < ND);
            const bool zok_nxt = (i + 1 < NSTEP) && (zt_cur + 1 >= 0) && (zt_cur + 1 < ND);

            // ---------- P1: A(i+1)  ||  C(i) ----------
            if (zok_nxt) DO_A(zt_cur + 1);
            if (zok_cur) DO_C();
            __syncthreads();

            // ---------- P2: B(i+1)  ||  D(i) ----------
            if (zok_nxt) DO_B();
            {
#pragma unroll
                for (int f = 0; f < 5; ++f) {
                    const float v = zok_cur ? vsum[f][ty][tx] : 0.f;
                    acc[f] += v - ring[f][jj];
                    ring[f][jj] = v;
                }
                const int zout = z0 + i - 8;
                if (i >= 8 && zout < ND) {
                    const float Is = acc[0], Js = acc[1];
                    const float I2 = acc[2], J2 = acc[3], IJ = acc[4];
                    const float inv = 1.0f / 729.0f;
                    const float uI = Is * inv, uJ = Js * inv;
                    const float cross = IJ - uJ * Is - uI * Js + uI * uJ * 729.0f;
                    const float Iv = I2 - 2.0f * uI * Is + uI * uI * 729.0f;
                    const float Jv = J2 - 2.0f * uJ * Js + uJ * uJ * 729.0f;
                    partial += cross * cross / (Iv * Jv + 1e-5f);
                }
            }
            __syncthreads();
        }
    }

    // ---------- reduction: wave shfl -> double atomic ----------
    double dp = (double)partial;
#pragma unroll
    for (int off = 32; off > 0; off >>= 1)
        dp += __shfl_down(dp, off, 64);
    if ((tid & 63) == 0) atomicAdd(gacc, dp);
}

__global__ void ncc_fin(const double* __restrict__ gacc, float* __restrict__ out) {
    out[0] = (float)(-gacc[0] / (double)((long long)NB * ND * NH * NW));
}

extern "C" void kernel_launch(void* const* d_in, const int* in_sizes, int n_in,
                              void* d_out, int out_size, void* d_ws, size_t ws_size,
                              hipStream_t stream) {
    const float* I = (const float*)d_in[0];   // y_true
    const float* J = (const float*)d_in[1];   // y_pred
    double* ws = (double*)d_ws;

    hipMemsetAsync(d_ws, 0, sizeof(double), stream);   // graph-capture safe

    dim3 grid((NW / TW) * (NH / TH), ZCHUNKS, NB);     // 60 x 9 x 2 = 1080 blocks
    ncc_main<<<grid, NTH, 0, stream>>>(I, J, ws);
    ncc_fin<<<1, 1, 0, stream>>>(ws, (float*)d_out);
}

// Round 3
// 107.133 us; speedup vs baseline: 1.9976x; 1.9976x over previous
//
#include <hip/hip_runtime.h>

// NCC loss, fused single pass, z-unrolled x2, 2-barrier pipelined superstep.
// Volume [B=2][1][D=160][H=192][W=160] fp32. Window 9^3, zero-padded, /729.
// Per block: tile TH=16 x TW=32 (H,W), stream ZC=40 z-planes (NSTEP=48, 24 supersteps).
// Superstep s = planes (2s, 2s+1):
//   P1 = { A(s+1): global->LDS raw I,J (2 planes, 2 loads/thread in flight)
//          || C(s): H-axis 9-tap hsum->vsum (both planes) }
//   P2 = { B(s+1): products + W-axis 9-tap raw->hsum (both planes)
//          || D(s): per-pixel z-ring + cc epilogue (both planes) }
// Single-buffered: every RAW/WAR pair spans exactly one barrier.

#define NB 2
#define ND 160
#define NH 192
#define NW 160
#define TH 16
#define TW 32
#define ZC 40
#define NSTEP (ZC + 8)     // 48 planes touched per chunk
#define NSUP (NSTEP / 2)   // 24 supersteps
#define ZCHUNKS (ND / ZC)  // 4
#define HR (TH + 8)        // 24 halo rows
#define RSTR 44            // raw row stride (40 used, mult of 4 for b128)
#define HSTR 36            // hsum row stride (32 used)
#define HROWS (HR + 1)     // +1 row pad: field stride 900 % 32 = 4
#define VSTR 36
#define VROWS (TH + 1)     // field stride 612 % 32 = 4
#define NTH 512

__device__ __forceinline__ float4 f4add(float4 a, float4 b) {
    return make_float4(a.x + b.x, a.y + b.y, a.z + b.z, a.w + b.w);
}
__device__ __forceinline__ float4 f4sub(float4 a, float4 b) {
    return make_float4(a.x - b.x, a.y - b.y, a.z - b.z, a.w - b.w);
}

__global__ __launch_bounds__(NTH, 4) void ncc_main(
        const float* __restrict__ I, const float* __restrict__ J,
        double* __restrict__ gacc) {
    __shared__ float raw[2][2][HR][RSTR];      // [plane][field] 16.9 KB
    __shared__ float hsum[2][5][HROWS][HSTR];  // 36.0 KB
    __shared__ float vsum[2][5][VROWS][VSTR];  // 24.5 KB   total ~77 KB -> 2 blk/CU

    const int tid = threadIdx.x;
    const int tx = tid & 31;
    const int ty = tid >> 5;

    const int tilesW = NW / TW;                 // 5
    const int tileW = blockIdx.x % tilesW;
    const int tileH = blockIdx.x / tilesW;      // 0..11
    const int w0 = tileW * TW;
    const int h0 = tileH * TH;
    const int z0 = blockIdx.y * ZC;
    const size_t volBase = (size_t)blockIdx.z * ND * NH * NW;

    // ---- A decode: 480 threads = 2 planes x 240 slots (24 rows x 10 float4).
    //      Each thread loads BOTH fields (I and J) for its slot: 2 loads in flight.
    const bool a_on = (tid < 480);
    const int a_p = (tid >= 240) ? 1 : 0;
    const int a_slot = a_on ? (tid - a_p * 240) : 0;
    const int a_r = a_slot / 10;
    const int a_c = (a_slot - a_r * 10) * 4;
    const int a_h = h0 - 4 + a_r;
    const int a_w = w0 - 4 + a_c;   // W edges mult of 4: float4 fully in or out
    const bool a_hw = a_on && a_h >= 0 && a_h < NH && a_w >= 0 && a_w < NW;
    const size_t a_goff = (size_t)a_h * NW + a_w;

    // ---- B decode: 480 threads = 2 planes x (5 fields x 24 rows x 2 halves)
    const bool b_on = (tid < 480);
    const int b_p = (tid >= 240) ? 1 : 0;
    const int b_rem = b_on ? (tid - b_p * 240) : 0;
    const int b_f = b_rem / 48;
    const int b_rr = b_rem - b_f * 48;
    const int b_r = b_rr >> 1;
    const int b_c0 = (b_rr & 1) << 4;
    const float* b_srcA = &raw[b_p][(b_f == 1 || b_f == 3) ? 1 : 0][b_r][b_c0];
    const float* b_srcB = &raw[b_p][1][b_r][b_c0];
    const bool b_sq = (b_f == 2 || b_f == 3);
    const bool b_ij = (b_f == 4);
    float* b_dst = &hsum[b_p][b_f][b_r][b_c0];

    // ---- C decode: 320 threads = 2 planes x (5 fields x 8 colgrp x 4 strips)
    const bool c_on = (tid < 320);
    const int c_p = (tid >= 160) ? 1 : 0;
    const int c_rem = c_on ? (tid - c_p * 160) : 0;
    const int c_f = c_rem >> 5;
    const int c_cg = (c_rem & 31) >> 2;
    const int c_r0 = (c_rem & 3) << 2;
    const int c_c0 = c_cg << 2;
    const float* c_src = &hsum[c_p][c_f][c_r0][c_c0];
    float* c_dst = &vsum[c_p][c_f][c_r0][c_c0];

#define DO_A(ztbase) do {                                                      \
    const int zt_ = (ztbase) + a_p;                                            \
    float4 vI = make_float4(0.f, 0.f, 0.f, 0.f), vJ = vI;                      \
    if (a_hw && zt_ >= 0 && zt_ < ND) {                                        \
        const size_t gi = volBase + (size_t)zt_ * (NH * NW) + a_goff;          \
        vI = *(const float4*)(I + gi);                                         \
        vJ = *(const float4*)(J + gi);                                         \
    }                                                                          \
    if (a_on) {                                                                \
        *(float4*)&raw[a_p][0][a_r][a_c] = vI;                                 \
        *(float4*)&raw[a_p][1][a_r][a_c] = vJ;                                 \
    }                                                                          \
} while (0)

#define DO_B() do { if (b_on) {                                                \
    float p[24];                                                               \
    _Pragma("unroll") for (int k = 0; k < 6; ++k)                              \
        *(float4*)&p[k * 4] = *(const float4*)(b_srcA + k * 4);                \
    if (b_sq) { _Pragma("unroll") for (int k = 0; k < 24; ++k) p[k] *= p[k]; } \
    if (b_ij) { _Pragma("unroll") for (int k = 0; k < 6; ++k) {                \
        float4 q = *(const float4*)(b_srcB + k * 4);                           \
        p[k*4+0] *= q.x; p[k*4+1] *= q.y; p[k*4+2] *= q.z; p[k*4+3] *= q.w; } }\
    float s = p[0];                                                            \
    _Pragma("unroll") for (int k = 1; k < 9; ++k) s += p[k];                   \
    _Pragma("unroll") for (int g = 0; g < 4; ++g) {                            \
        float4 ov; ov.x = s;                                                   \
        s += p[g*4+9]  - p[g*4+0]; ov.y = s;                                   \
        s += p[g*4+10] - p[g*4+1]; ov.z = s;                                   \
        s += p[g*4+11] - p[g*4+2]; ov.w = s;                                   \
        *(float4*)(b_dst + g * 4) = ov;                                        \
        if (g < 3) s += p[g*4+12] - p[g*4+3];                                  \
    } } } while (0)

#define DO_C() do { if (c_on) {                                                \
    float4 r0v = *(const float4*)(c_src + 0 * HSTR);                           \
    float4 r1v = *(const float4*)(c_src + 1 * HSTR);                           \
    float4 r2v = *(const float4*)(c_src + 2 * HSTR);                           \
    float4 s4 = f4add(f4add(r0v, r1v), r2v);                                   \
    _Pragma("unroll") for (int k = 3; k < 9; ++k)                              \
        s4 = f4add(s4, *(const float4*)(c_src + k * HSTR));                    \
    *(float4*)(c_dst + 0 * VSTR) = s4;                                         \
    s4 = f4sub(f4add(s4, *(const float4*)(c_src +  9 * HSTR)), r0v);           \
    *(float4*)(c_dst + 1 * VSTR) = s4;                                         \
    s4 = f4sub(f4add(s4, *(const float4*)(c_src + 10 * HSTR)), r1v);           \
    *(float4*)(c_dst + 2 * VSTR) = s4;                                         \
    s4 = f4sub(f4add(s4, *(const float4*)(c_src + 11 * HSTR)), r2v);           \
    *(float4*)(c_dst + 3 * VSTR) = s4;                                         \
} } while (0)

    float ring[5][9];
    float acc[5];
#pragma unroll
    for (int f = 0; f < 5; ++f) {
        acc[f] = 0.f;
#pragma unroll
        for (int k = 0; k < 9; ++k) ring[f][k] = 0.f;
    }
    float partial = 0.f;

    // ---- prologue: superstep 0 (planes z0-4, z0-3) through A and B ----
    DO_A(z0 - 4);
    __syncthreads();
    DO_B();
    __syncthreads();

    // ---- main loop: 24 supersteps; outer blocks start at ss % 9 == 0 so the
    //      ring slot (2*(ss+jj)+p) % 9 == (2*jj+p) % 9 is unroll-static.
#pragma unroll 1
    for (int ss = 0; ss < NSUP; ss += 9) {
#pragma unroll
        for (int jj = 0; jj < 9; ++jj) {
            const int s = ss + jj;
            if (s < NSUP) {
                const int sl0 = (2 * jj) % 9;
                const int sl1 = (2 * jj + 1) % 9;
                const int i0 = 2 * s;
                const int zt0 = z0 - 4 + i0;
                const bool zok0 = (zt0 >= 0) && (zt0 < ND);
                const bool zok1 = (zt0 + 1 >= 0) && (zt0 + 1 < ND);
                const bool more = (s + 1 < NSUP);

                // ---------- P1: A(s+1) || C(s) ----------
                if (more) DO_A(zt0 + 2);
                DO_C();
                __syncthreads();

                // ---------- P2: B(s+1) || D(s) ----------
                if (more) DO_B();
                {
                    // plane 0 of pair
#pragma unroll
                    for (int f = 0; f < 5; ++f) {
                        const float v = zok0 ? vsum[0][f][ty][tx] : 0.f;
                        acc[f] += v - ring[f][sl0];
                        ring[f][sl0] = v;
                    }
                    if (i0 >= 8) {
                        const float Is = acc[0], Js = acc[1];
                        const float I2 = acc[2], J2 = acc[3], IJ = acc[4];
                        const float inv = 1.0f / 729.0f;
                        const float uI = Is * inv, uJ = Js * inv;
                        const float cross = IJ - uJ * Is - uI * Js + uI * uJ * 729.0f;
                        const float Iv = I2 - 2.0f * uI * Is + uI * uI * 729.0f;
                        const float Jv = J2 - 2.0f * uJ * Js + uJ * uJ * 729.0f;
                        partial += cross * cross / (Iv * Jv + 1e-5f);
                    }
                    // plane 1 of pair
#pragma unroll
                    for (int f = 0; f < 5; ++f) {
                        const float v = zok1 ? vsum[1][f][ty][tx] : 0.f;
                        acc[f] += v - ring[f][sl1];
                        ring[f][sl1] = v;
                    }
                    if (i0 + 1 >= 8) {
                        const float Is = acc[0], Js = acc[1];
                        const float I2 = acc[2], J2 = acc[3], IJ = acc[4];
                        const float inv = 1.0f / 729.0f;
                        const float uI = Is * inv, uJ = Js * inv;
                        const float cross = IJ - uJ * Is - uI * Js + uI * uJ * 729.0f;
                        const float Iv = I2 - 2.0f * uI * Is + uI * uI * 729.0f;
                        const float Jv = J2 - 2.0f * uJ * Js + uJ * uJ * 729.0f;
                        partial += cross * cross / (Iv * Jv + 1e-5f);
                    }
                }
                __syncthreads();
            }
        }
    }

    // ---------- reduction: wave shfl -> double atomic ----------
    double dp = (double)partial;
#pragma unroll
    for (int off = 32; off > 0; off >>= 1)
        dp += __shfl_down(dp, off, 64);
    if ((tid & 63) == 0) atomicAdd(gacc, dp);
}

__global__ void ncc_fin(const double* __restrict__ gacc, float* __restrict__ out) {
    out[0] = (float)(-gacc[0] / (double)((long long)NB * ND * NH * NW));
}

extern "C" void kernel_launch(void* const* d_in, const int* in_sizes, int n_in,
                              void* d_out, int out_size, void* d_ws, size_t ws_size,
                              hipStream_t stream) {
    const float* I = (const float*)d_in[0];   // y_true
    const float* J = (const float*)d_in[1];   // y_pred
    double* ws = (double*)d_ws;

    hipMemsetAsync(d_ws, 0, sizeof(double), stream);   // graph-capture safe

    dim3 grid((NW / TW) * (NH / TH), ZCHUNKS, NB);     // 60 x 4 x 2 = 480 blocks
    ncc_main<<<grid, NTH, 0, stream>>>(I, J, ws);
    ncc_fin<<<1, 1, 0, stream>>>(ws, (float*)d_out);
}

// Round 4
// 102.544 us; speedup vs baseline: 2.0870x; 1.0448x over previous
//
#include <hip/hip_runtime.h>

// NCC loss, fused single pass. R4: no-vmcnt-drain schedule (raw s_barrier +
// lgkmcnt-only fences), reg-staged global loads issued 1 superstep ahead
// (compiler emits counted vmcnt at the ds_write), B-phase field-fusion.
// Volume [B=2][1][D=160][H=192][W=160] fp32. Window 9^3, zero-padded, /729.
// Per block: tile TH=16 x TW=32 (H,W), ZC=40 z-planes (24 supersteps of 2).
// Superstep s:  [ISSUE(s+1) | C(s)]  BAR  [D(s) | STAGE(s+1)]  BAR  [B(s+1)] BAR
// All LDS single-buffered: each producer->consumer / WAR pair spans >=1 barrier.

#define NB 2
#define ND 160
#define NH 192
#define NW 160
#define TH 16
#define TW 32
#define ZC 40
#define NSTEP (ZC + 8)     // 48 planes touched per chunk
#define NSUP (NSTEP / 2)   // 24 supersteps
#define ZCHUNKS (ND / ZC)  // 4
#define HR (TH + 8)        // 24 halo rows
#define RSTR 44
#define HSTR 36
#define HROWS (HR + 1)     // 25 (field stride 900%32=4)
#define VSTR 36
#define VROWS (TH + 1)     // 17
#define NTH 512

__device__ __forceinline__ float4 f4add(float4 a, float4 b) {
    return make_float4(a.x + b.x, a.y + b.y, a.z + b.z, a.w + b.w);
}
__device__ __forceinline__ float4 f4sub(float4 a, float4 b) {
    return make_float4(a.x - b.x, a.y - b.y, a.z - b.z, a.w - b.w);
}

// Publish fence: drain own LDS writes, then raw barrier. No vmcnt drain --
// in-flight global loads keep flying across workgroup syncs (T4 mechanism).
__device__ __forceinline__ void barw() {
    asm volatile("s_waitcnt lgkmcnt(0)" ::: "memory");
    __builtin_amdgcn_s_barrier();
    asm volatile("" ::: "memory");
}

__global__ __launch_bounds__(NTH, 4) void ncc_main(
        const float* __restrict__ I, const float* __restrict__ J,
        double* __restrict__ gacc) {
    __shared__ float raw[2][2][HR][RSTR];      // [plane][field] 16.9 KB
    __shared__ float hsum[2][5][HROWS][HSTR];  // 36.0 KB
    __shared__ float vsum[2][5][VROWS][VSTR];  // 24.5 KB  total ~77 KB, 2 blk/CU

    const int tid = threadIdx.x;
    const int tx = tid & 31;
    const int ty = tid >> 5;

    const int tilesW = NW / TW;                 // 5
    const int tileW = blockIdx.x % tilesW;
    const int tileH = blockIdx.x / tilesW;      // 0..11
    const int w0 = tileW * TW;
    const int h0 = tileH * TH;
    const int z0 = blockIdx.y * ZC;
    const size_t volBase = (size_t)blockIdx.z * ND * NH * NW;

    // ---- A decode: 480 threads = 2 planes x 240 slots (24 rows x 10 float4)
    const bool a_on = (tid < 480);
    const int a_p = (a_on && tid >= 240) ? 1 : 0;
    const int a_slot = a_on ? (tid - a_p * 240) : 0;
    const int a_r = a_slot / 10;
    const int a_c = (a_slot - a_r * 10) * 4;
    const int a_h = h0 - 4 + a_r;
    const int a_w = w0 - 4 + a_c;   // W edges mult of 4: float4 fully in or out
    const bool a_hw = a_on && a_h >= 0 && a_h < NH && a_w >= 0 && a_w < NW;
    const size_t a_goff = (size_t)a_h * NW + a_w;

    // ---- B decode (field-fused): 192 threads = 2 planes x 24 rows x 4 quarters
    const bool b_on = (tid < 192);
    const int bp = (b_on && tid >= 96) ? 1 : 0;
    const int b_rem = b_on ? (tid - bp * 96) : 0;
    const int br = b_rem >> 2;
    const int bq8 = (b_rem & 3) << 3;           // output col base (0,8,16,24)

    // ---- C decode: 320 threads = 2 planes x (5 fields x 8 colgrp x 4 strips)
    const bool c_on = (tid < 320);
    const int c_p = (c_on && tid >= 160) ? 1 : 0;
    const int c_rem = c_on ? (tid - c_p * 160) : 0;
    const int c_f = c_rem >> 5;
    const int c_cg = (c_rem & 31) >> 2;
    const int c_r0 = (c_rem & 3) << 2;
    const int c_c0 = c_cg << 2;
    const float* c_src = &hsum[c_p][c_f][c_r0][c_c0];
    float* c_dst = &vsum[c_p][c_f][c_r0][c_c0];

    float4 gI = make_float4(0.f, 0.f, 0.f, 0.f), gJ = gI;

// issue global loads for superstep t into regs (no wait)
#define ISSUE(t) do {                                                          \
    const int zt_ = z0 - 4 + 2 * (t) + a_p;                                    \
    gI = make_float4(0.f, 0.f, 0.f, 0.f); gJ = gI;                             \
    if (a_hw && zt_ >= 0 && zt_ < ND) {                                        \
        const size_t gi = volBase + (size_t)zt_ * (NH * NW) + a_goff;          \
        gI = *(const float4*)(I + gi);                                         \
        gJ = *(const float4*)(J + gi);                                         \
    }                                                                          \
} while (0)

// write staged regs to LDS (compiler inserts counted vmcnt here)
#define STAGE() do { if (a_on) {                                               \
    *(float4*)&raw[a_p][0][a_r][a_c] = gI;                                     \
    *(float4*)&raw[a_p][1][a_r][a_c] = gJ;                                     \
} } while (0)

// B: read I,J windows once, compute all 5 product sliding sums (field-fused)
#define BSLIDE(EXPR, F) do {                                                   \
    float s = 0.f;                                                             \
    _Pragma("unroll") for (int k = 0; k < 9; ++k) s += (EXPR(k));              \
    float o[8]; o[0] = s;                                                      \
    _Pragma("unroll") for (int j = 1; j < 8; ++j) {                            \
        s += (EXPR(j + 8)) - (EXPR(j - 1)); o[j] = s; }                        \
    *(float4*)&hsum[bp][F][br][bq8]     = *(float4*)&o[0];                     \
    *(float4*)&hsum[bp][F][br][bq8 + 4] = *(float4*)&o[4];                     \
} while (0)
#define E_I(k)  pI[k]
#define E_J(k)  pJ[k]
#define E_I2(k) (pI[k] * pI[k])
#define E_J2(k) (pJ[k] * pJ[k])
#define E_IJ(k) (pI[k] * pJ[k])

#define DO_B() do { if (b_on) {                                                \
    float pI[16], pJ[16];                                                      \
    _Pragma("unroll") for (int k = 0; k < 4; ++k) {                            \
        *(float4*)&pI[k * 4] = *(const float4*)&raw[bp][0][br][bq8 + k * 4];   \
        *(float4*)&pJ[k * 4] = *(const float4*)&raw[bp][1][br][bq8 + k * 4];   \
    }                                                                          \
    BSLIDE(E_I, 0); BSLIDE(E_J, 1); BSLIDE(E_I2, 2);                           \
    BSLIDE(E_J2, 3); BSLIDE(E_IJ, 4);                                          \
} } while (0)

#define DO_C() do { if (c_on) {                                                \
    float4 r0v = *(const float4*)(c_src + 0 * HSTR);                           \
    float4 r1v = *(const float4*)(c_src + 1 * HSTR);                           \
    float4 r2v = *(const float4*)(c_src + 2 * HSTR);                           \
    float4 s4 = f4add(f4add(r0v, r1v), r2v);                                   \
    _Pragma("unroll") for (int k = 3; k < 9; ++k)                              \
        s4 = f4add(s4, *(const float4*)(c_src + k * HSTR));                    \
    *(float4*)(c_dst + 0 * VSTR) = s4;                                         \
    s4 = f4sub(f4add(s4, *(const float4*)(c_src +  9 * HSTR)), r0v);           \
    *(float4*)(c_dst + 1 * VSTR) = s4;                                         \
    s4 = f4sub(f4add(s4, *(const float4*)(c_src + 10 * HSTR)), r1v);           \
    *(float4*)(c_dst + 2 * VSTR) = s4;                                         \
    s4 = f4sub(f4add(s4, *(const float4*)(c_src + 11 * HSTR)), r2v);           \
    *(float4*)(c_dst + 3 * VSTR) = s4;                                         \
} } while (0)

    float ring[5][9];
    float acc[5];
#pragma unroll
    for (int f = 0; f < 5; ++f) {
        acc[f] = 0.f;
#pragma unroll
        for (int k = 0; k < 9; ++k) ring[f][k] = 0.f;
    }
    float partial = 0.f;

    // ---- prologue: stage + B for superstep 0 ----
    ISSUE(0);
    STAGE();
    barw();
    DO_B();
    barw();

#pragma unroll 1
    for (int ss = 0; ss < NSUP; ss += 9) {
#pragma unroll
        for (int jj = 0; jj < 9; ++jj) {
            const int s = ss + jj;
            if (s < NSUP) {
                const int sl0 = (2 * jj) % 9;        // static ring slots
                const int sl1 = (2 * jj + 1) % 9;
                const int i0 = 2 * s;
                const int zt0 = z0 - 4 + i0;
                const bool zok0 = (zt0 >= 0) && (zt0 < ND);
                const bool zok1 = (zt0 + 1 >= 0) && (zt0 + 1 < ND);
                const bool more = (s + 1 < NSUP);

                // ---- [ISSUE(s+1) | C(s)] ----
                if (more) ISSUE(s + 1);
                DO_C();
                barw();

                // ---- [D(s) | STAGE(s+1)] ----
                {
#pragma unroll
                    for (int f = 0; f < 5; ++f) {
                        const float v = zok0 ? vsum[0][f][ty][tx] : 0.f;
                        acc[f] += v - ring[f][sl0];
                        ring[f][sl0] = v;
                    }
                    if (i0 >= 8) {
                        const float Is = acc[0], Js = acc[1];
                        const float I2 = acc[2], J2 = acc[3], IJ = acc[4];
                        const float inv = 1.0f / 729.0f;
                        const float uI = Is * inv, uJ = Js * inv;
                        const float cross = IJ - uJ * Is - uI * Js + uI * uJ * 729.0f;
                        const float Iv = I2 - 2.0f * uI * Is + uI * uI * 729.0f;
                        const float Jv = J2 - 2.0f * uJ * Js + uJ * uJ * 729.0f;
                        partial += cross * cross / (Iv * Jv + 1e-5f);
                    }
#pragma unroll
                    for (int f = 0; f < 5; ++f) {
                        const float v = zok1 ? vsum[1][f][ty][tx] : 0.f;
                        acc[f] += v - ring[f][sl1];
                        ring[f][sl1] = v;
                    }
                    if (i0 + 1 >= 8) {
                        const float Is = acc[0], Js = acc[1];
                        const float I2 = acc[2], J2 = acc[3], IJ = acc[4];
                        const float inv = 1.0f / 729.0f;
                        const float uI = Is * inv, uJ = Js * inv;
                        const float cross = IJ - uJ * Is - uI * Js + uI * uJ * 729.0f;
                        const float Iv = I2 - 2.0f * uI * Is + uI * uI * 729.0f;
                        const float Jv = J2 - 2.0f * uJ * Js + uJ * uJ * 729.0f;
                        partial += cross * cross / (Iv * Jv + 1e-5f);
                    }
                }
                if (more) STAGE();
                barw();

                // ---- [B(s+1)] ----
                if (more) DO_B();
                barw();
            }
        }
    }

    // ---------- reduction: wave shfl -> double atomic ----------
    double dp = (double)partial;
#pragma unroll
    for (int off = 32; off > 0; off >>= 1)
        dp += __shfl_down(dp, off, 64);
    if ((tid & 63) == 0) atomicAdd(gacc, dp);
}

__global__ void ncc_fin(const double* __restrict__ gacc, float* __restrict__ out) {
    out[0] = (float)(-gacc[0] / (double)((long long)NB * ND * NH * NW));
}

extern "C" void kernel_launch(void* const* d_in, const int* in_sizes, int n_in,
                              void* d_out, int out_size, void* d_ws, size_t ws_size,
                              hipStream_t stream) {
    const float* I = (const float*)d_in[0];   // y_true
    const float* J = (const float*)d_in[1];   // y_pred
    double* ws = (double*)d_ws;

    hipMemsetAsync(d_ws, 0, sizeof(double), stream);   // graph-capture safe

    dim3 grid((NW / TW) * (NH / TH), ZCHUNKS, NB);     // 60 x 4 x 2 = 480 blocks
    ncc_main<<<grid, NTH, 0, stream>>>(I, J, ws);
    ncc_fin<<<1, 1, 0, stream>>>(ws, (float*)d_out);
}